// Round 5
// baseline (707.529 us; speedup 1.0000x reference)
//
#include <hip/hip_runtime.h>
#include <hip/hip_bf16.h>
#include <math.h>

#define B_ 8
#define C_ 64
#define H_ 128
#define W_ 128
#define HW_ (H_*W_)
#define HP_ 130
#define WP_ 130
#define XPLANE_ (HP_*WP_*64)     // padded NHWC plane per batch (halfwords)

typedef __attribute__((ext_vector_type(8))) short bf16x8;
typedef __attribute__((ext_vector_type(4))) float f32x4;
typedef __attribute__((ext_vector_type(4))) unsigned int u32x4;

// ---------------------------------------------------------------------------
__global__ __launch_bounds__(256)
void zero_k(unsigned int* __restrict__ p, int n)
{
    for (int i = blockIdx.x*256 + threadIdx.x; i < n; i += gridDim.x*256)
        p[i] = 0u;
}

// ---------------------------------------------------------------------------
// x NCHW fp32 -> xTp padded NHWC bf16 (interior only; halo pre-zeroed).
// ---------------------------------------------------------------------------
__global__ __launch_bounds__(256)
void xpose_x_k(const float* __restrict__ x, __hip_bfloat16* __restrict__ xTp)
{
    __shared__ float tile[64][65];
    const int tid = threadIdx.x;
    const int w0 = blockIdx.x*64, h = blockIdx.y, b = blockIdx.z;
    const float* xb = x + (size_t)b*64*HW_;
    for (int i = tid; i < 4096; i += 256){
        const int c = i >> 6, px = i & 63;
        tile[c][px] = xb[(size_t)c*HW_ + h*W_ + w0 + px];
    }
    __syncthreads();
    __hip_bfloat16* ob = xTp + (size_t)b*XPLANE_;
    for (int i = tid; i < 512; i += 256){
        const int px = i >> 3, cs = i & 7;
        union { bf16x8 v; __hip_bfloat16 h8[8]; } R;
#pragma unroll
        for (int j=0;j<8;j++) R.h8[j] = __float2bfloat16(tile[cs*8+j][px]);
        *(bf16x8*)&ob[((size_t)(h+1)*WP_ + (w0+px+1))*64 + cs*8] = R.v;
    }
}

// ---------------------------------------------------------------------------
// Weight transpose+cast: w fp32 [O][64][9] -> wT bf16 [9][OPAD][64]
// ---------------------------------------------------------------------------
__global__ __launch_bounds__(256)
void cast_w_k(const float* __restrict__ w, __hip_bfloat16* __restrict__ wT,
              int O, int OPAD)
{
    const int idx = blockIdx.x*256 + threadIdx.x;
    if (idx >= 9*O*64) return;
    const int k = idx / (O*64);
    const int rem = idx - k*O*64;
    const int o = rem >> 6, c = rem & 63;
    wT[((size_t)k*OPAD + o)*64 + c] = __float2bfloat16(w[((size_t)o*64 + c)*9 + k]);
}

// ---------------------------------------------------------------------------
// Implicit-GEMM 3x3 conv via MFMA. Zero LDS, zero barriers: A-fragments are
// loaded directly from global wT (144KB max, L2-broadcast, L1-reused by all
// waves); B = direct 16B NHWC loads at the tap-shifted position.
// D[co][px], px = wid*16 + (lane&15).
// ---------------------------------------------------------------------------
enum OutMode { OUT_NHWC_PAD_RELU, OUT_NCHW_F32, OUT_NCHW_BF16 };

template<int G, int CO_TOT, OutMode MODE>
__global__ __launch_bounds__(256)
void conv_mfma_k(const __hip_bfloat16* __restrict__ xT,
                 const __hip_bfloat16* __restrict__ wT, int o_total,
                 void* __restrict__ outp)
{
    const int tid = threadIdx.x, lane = tid & 63, wid = tid >> 6;
    const int l15 = lane & 15, khi = lane >> 4;
    const int ow0 = blockIdx.x*64, oh = blockIdx.y;
    const int b = blockIdx.z & 7, cob = blockIdx.z >> 3;
    const int px = wid*16 + l15;
    const __hip_bfloat16* xb = xT + (size_t)b*XPLANE_;

    f32x4 acc[G];
    const f32x4 vz = {0.f,0.f,0.f,0.f};
#pragma unroll
    for (int g=0; g<G; ++g) acc[g] = vz;

#pragma unroll
    for (int k=0; k<9; ++k){
        const int dy = k/3 - 1, dxk = k%3 - 1;
        const int base = (((oh+1+dy)*WP_) + (ow0+px+1+dxk))*64;
#pragma unroll
        for (int s=0; s<2; ++s){
            const bf16x8 bfr = *(const bf16x8*)&xb[base + s*32 + khi*8];
#pragma unroll
            for (int g=0; g<G; ++g){
                const bf16x8 afr = *(const bf16x8*)
                    &wT[((size_t)k*o_total + cob*64 + g*16 + l15)*64 + s*32 + khi*8];
                acc[g] = __builtin_amdgcn_mfma_f32_16x16x32_bf16(afr, bfr, acc[g], 0,0,0);
            }
        }
    }
    // ---- epilogue ----
    if (MODE == OUT_NHWC_PAD_RELU){
        __hip_bfloat16* ob = (__hip_bfloat16*)outp + (size_t)b*XPLANE_;
        const size_t orow = ((size_t)(oh+1)*WP_ + (ow0+px+1))*64;
#pragma unroll
        for (int g=0; g<G; ++g){
            union { short4 s4; __hip_bfloat16 h[4]; } o4;
#pragma unroll
            for (int r=0;r<4;r++) o4.h[r] = __float2bfloat16(fmaxf(acc[g][r], 0.f));
            *(short4*)&ob[orow + g*16 + khi*4] = o4.s4;
        }
    } else if (MODE == OUT_NCHW_F32){
        float* ob = (float*)outp;
#pragma unroll
        for (int g=0; g<G; ++g)
#pragma unroll
            for (int r=0;r<4;r++){
                const int co = cob*64 + g*16 + khi*4 + r;
                if (co < CO_TOT)
                    ob[(((size_t)b*CO_TOT + co)*H_ + oh)*W_ + ow0 + px] = acc[g][r];
            }
    } else {
        __hip_bfloat16* ob = (__hip_bfloat16*)outp;
#pragma unroll
        for (int g=0; g<G; ++g)
#pragma unroll
            for (int r=0;r<4;r++){
                const int co = cob*64 + g*16 + khi*4 + r;
                ob[(((size_t)b*CO_TOT + co)*H_ + oh)*W_ + ow0 + px] = __float2bfloat16(acc[g][r]);
            }
    }
}

// ---------------------------------------------------------------------------
// 4-corner bilinear blend of 8 consecutive channels (NHWC bf16) -> bf16x8.
// ---------------------------------------------------------------------------
__device__ __forceinline__ bf16x8 blend4(const __hip_bfloat16* __restrict__ xb,
                                         int a00, int dxo, int dro, float4 w)
{
    const u32x4 q00 = *(const u32x4*)(xb + a00);
    const u32x4 q01 = *(const u32x4*)(xb + a00 + dxo);
    const u32x4 q10 = *(const u32x4*)(xb + a00 + dro);
    const u32x4 q11 = *(const u32x4*)(xb + a00 + dro + dxo);
    union { bf16x8 v; __hip_bfloat16 h[8]; } R;
#pragma unroll
    for (int p=0;p<4;++p){
        const float l00 = __uint_as_float(q00[p]<<16), h00 = __uint_as_float(q00[p]&0xFFFF0000u);
        const float l01 = __uint_as_float(q01[p]<<16), h01 = __uint_as_float(q01[p]&0xFFFF0000u);
        const float l10 = __uint_as_float(q10[p]<<16), h10 = __uint_as_float(q10[p]&0xFFFF0000u);
        const float l11 = __uint_as_float(q11[p]<<16), h11 = __uint_as_float(q11[p]&0xFFFF0000u);
        R.h[2*p  ] = __float2bfloat16(w.x*l00 + w.y*l01 + w.z*l10 + w.w*l11);
        R.h[2*p+1] = __float2bfloat16(w.x*h00 + w.y*h01 + w.z*h10 + w.w*h11);
    }
    return R.v;
}

// ---------------------------------------------------------------------------
// Fused deformable conv (MFMA) + softmax attention. B-fragments built in
// registers from 16B NHWC corner gathers; A-fragments loaded directly from
// global wTd (no wA tile). Only 4 barriers total (meta staging per dk).
// ---------------------------------------------------------------------------
__global__ __launch_bounds__(256)
void deform_att_k(const __hip_bfloat16* __restrict__ xT,
                  const float* __restrict__ off,
                  const __hip_bfloat16* __restrict__ att,
                  const __hip_bfloat16* __restrict__ wTd,   // [9][128][64]
                  float* __restrict__ out)
{
    __shared__ int4   mI[9][64];
    __shared__ float4 mW[9][64];
    const int tid = threadIdx.x, lane = tid & 63, wid = tid >> 6;
    const int l15 = lane & 15, khi = lane >> 4;
    const int ow0 = blockIdx.x*64, oh = blockIdx.y, b = blockIdx.z;
    const int px = wid*16 + l15;
    const __hip_bfloat16* xb = xT + (size_t)b*XPLANE_;

    f32x4 acc[2][4];
    const f32x4 vz = {0.f,0.f,0.f,0.f};
#pragma unroll
    for (int d=0; d<2; ++d)
#pragma unroll
        for (int g=0; g<4; ++g) acc[d][g] = vz;

    for (int dk=0; dk<2; ++dk){
        __syncthreads();   // prior dk's meta reads complete before overwrite
        for (int e=tid; e<576; e+=256){
            const int k = e >> 6, p = e & 63;
            const float oy = off[(((size_t)b*36 + dk*18 + 2*k  )*H_ + oh)*W_ + ow0 + p];
            const float ox = off[(((size_t)b*36 + dk*18 + 2*k+1)*H_ + oh)*W_ + ow0 + p];
            const float py  = (float)(oh  - 1 + (k/3))      + oy;
            const float pxx = (float)(ow0 + p - 1 + (k%3))  + ox;
            const float y0f = floorf(py), x0f = floorf(pxx);
            const float ay = py - y0f, ax = pxx - x0f;
            const int y0 = (int)y0f, x0 = (int)x0f;
            const int y1 = y0 + 1,   x1 = x0 + 1;
            const float my0 = (y0 >= 0 && y0 < H_) ? 1.f : 0.f;
            const float my1 = (y1 >= 0 && y1 < H_) ? 1.f : 0.f;
            const float mx0 = (x0 >= 0 && x0 < W_) ? 1.f : 0.f;
            const float mx1 = (x1 >= 0 && x1 < W_) ? 1.f : 0.f;
            const int y0c = min(max(y0,0),H_-1), y1c = min(max(y1,0),H_-1);
            const int x0c = min(max(x0,0),W_-1), x1c = min(max(x1,0),W_-1);
            const float wy0 = my0*(1.f-ay), wy1 = my1*ay;
            const float wx0 = mx0*(1.f-ax), wx1 = mx1*ax;
            mI[k][p] = make_int4(((y0c+1)*WP_ + (x0c+1))*64,
                                 (x1c-x0c)*64, (y1c-y0c)*WP_*64, 0);
            mW[k][p] = make_float4(wy0*wx0, wy0*wx1, wy1*wx0, wy1*wx1);
        }
        __syncthreads();   // meta visible
        for (int k=0; k<9; ++k){
            const int4   mi  = mI[k][px];
            const float4 mwt = mW[k][px];
#pragma unroll
            for (int s=0; s<2; ++s){
                const bf16x8 bfr = blend4(xb, mi.x + s*32 + khi*8, mi.y, mi.z, mwt);
#pragma unroll
                for (int g=0; g<4; ++g){
                    const bf16x8 afr = *(const bf16x8*)
                        &wTd[((size_t)k*128 + dk*64 + g*16 + l15)*64 + s*32 + khi*8];
                    acc[dk][g] = __builtin_amdgcn_mfma_f32_16x16x32_bf16(afr, bfr, acc[dk][g], 0,0,0);
                }
            }
        }
    }
    // ---- epilogue: softmax over the 2 dynamic branches + write ----
#pragma unroll
    for (int g=0; g<4; ++g)
#pragma unroll
        for (int r=0; r<4; ++r){
            const int co = g*16 + khi*4 + r;
            const float a0 = __bfloat162float(att[(((size_t)b*128      + co)*H_ + oh)*W_ + ow0 + px]);
            const float a1 = __bfloat162float(att[(((size_t)b*128 + 64 + co)*H_ + oh)*W_ + ow0 + px]);
            const float f0 = 1.f / (1.f + __expf(a1 - a0));
            out[(((size_t)b*64 + co)*H_ + oh)*W_ + ow0 + px] =
                acc[0][g][r]*f0 + acc[1][g][r]*(1.f - f0);
        }
}

// ---------------------------------------------------------------------------
extern "C" void kernel_launch(void* const* d_in, const int* in_sizes, int n_in,
                              void* d_out, int out_size, void* d_ws, size_t ws_size,
                              hipStream_t stream)
{
    const float* x  = (const float*)d_in[0];
    const float* w1 = (const float*)d_in[1];
    const float* w2 = (const float*)d_in[2];
    const float* w3 = (const float*)d_in[3];
    const float* wa = (const float*)d_in[4];
    const float* wd = (const float*)d_in[5];
    float* out = (float*)d_out;

    // ---- workspace layout (halfword units for bf16 regions) ----
    __hip_bfloat16* xTp  = (__hip_bfloat16*)d_ws;       // 8,652,800
    __hip_bfloat16* m1Tp = xTp  + (size_t)8652800;      // 8,652,800
    __hip_bfloat16* m2Tp = m1Tp + (size_t)8652800;      // 8,652,800
    __hip_bfloat16* wT1  = m2Tp + (size_t)8652800;      // 9*64*64   = 36864
    __hip_bfloat16* wT2  = wT1  + 36864;                // 36864
    __hip_bfloat16* wT3  = wT2  + 36864;                // 9*48*64   = 27648
    __hip_bfloat16* wTa  = wT3  + 27648;                // 9*128*64  = 73728
    __hip_bfloat16* wTd  = wTa  + 73728;                // 73728
    float*          offs = (float*)(wTd + 73728);       // 8*36*128*128 fp32
    __hip_bfloat16* att16 = m1Tp;   // aliases m1Tp+m2Tp (both dead by then)

    const dim3 blk(256);
    // zero padded NHWC buffers (halos) + wT3 pad rows
    zero_k<<<dim3(2048), blk, 0, stream>>>((unsigned int*)xTp, 12979200);
    zero_k<<<dim3(54),   blk, 0, stream>>>((unsigned int*)wT3, 13824);
    // layout transforms
    xpose_x_k<<<dim3(2,128,8), blk, 0, stream>>>(x, xTp);
    cast_w_k<<<dim3(144), blk, 0, stream>>>(w1, wT1,  64,  64);
    cast_w_k<<<dim3(144), blk, 0, stream>>>(w2, wT2,  64,  64);
    cast_w_k<<<dim3(81),  blk, 0, stream>>>(w3, wT3,  36,  48);
    cast_w_k<<<dim3(288), blk, 0, stream>>>(wa, wTa, 128, 128);
    cast_w_k<<<dim3(288), blk, 0, stream>>>(wd, wTd, 128, 128);
    // conv chain (implicit-GEMM MFMA, zero-barrier)
    conv_mfma_k<4,  64, OUT_NHWC_PAD_RELU><<<dim3(2,128,8),  blk, 0, stream>>>(xTp,  wT1,  64, m1Tp);
    conv_mfma_k<4,  64, OUT_NHWC_PAD_RELU><<<dim3(2,128,8),  blk, 0, stream>>>(m1Tp, wT2,  64, m2Tp);
    conv_mfma_k<3,  36, OUT_NCHW_F32     ><<<dim3(2,128,8),  blk, 0, stream>>>(m2Tp, wT3,  48, offs);
    conv_mfma_k<4, 128, OUT_NCHW_BF16    ><<<dim3(2,128,16), blk, 0, stream>>>(xTp,  wTa, 128, att16);
    // fused deformable conv + attention
    deform_att_k<<<dim3(2,128,8), blk, 0, stream>>>(xTp, offs, att16, wTd, out);
}

// Round 6
// 306.647 us; speedup vs baseline: 2.3073x; 2.3073x over previous
//
#include <hip/hip_runtime.h>
#include <hip/hip_bf16.h>
#include <math.h>

#define B_ 8
#define C_ 64
#define H_ 128
#define W_ 128
#define HW_ (H_*W_)
#define HP_ 130
#define WP_ 130
#define XPLANE_ (HP_*WP_*64)     // padded NHWC plane per batch (halfwords)

typedef __attribute__((ext_vector_type(8))) short bf16x8;
typedef __attribute__((ext_vector_type(4))) float f32x4;
typedef __attribute__((ext_vector_type(4))) unsigned int u32x4;

// ---------------------------------------------------------------------------
__global__ __launch_bounds__(256)
void zero_k(unsigned int* __restrict__ p, int n)
{
    for (int i = blockIdx.x*256 + threadIdx.x; i < n; i += gridDim.x*256)
        p[i] = 0u;
}

// ---------------------------------------------------------------------------
// x NCHW fp32 -> xTp padded NHWC bf16 (interior only; halo pre-zeroed).
// ---------------------------------------------------------------------------
__global__ __launch_bounds__(256)
void xpose_x_k(const float* __restrict__ x, __hip_bfloat16* __restrict__ xTp)
{
    __shared__ float tile[64][65];
    const int tid = threadIdx.x;
    const int w0 = blockIdx.x*64, h = blockIdx.y, b = blockIdx.z;
    const float* xb = x + (size_t)b*64*HW_;
    for (int i = tid; i < 4096; i += 256){
        const int c = i >> 6, px = i & 63;
        tile[c][px] = xb[(size_t)c*HW_ + h*W_ + w0 + px];
    }
    __syncthreads();
    __hip_bfloat16* ob = xTp + (size_t)b*XPLANE_;
    for (int i = tid; i < 512; i += 256){
        const int px = i >> 3, cs = i & 7;
        union { bf16x8 v; __hip_bfloat16 h8[8]; } R;
#pragma unroll
        for (int j=0;j<8;j++) R.h8[j] = __float2bfloat16(tile[cs*8+j][px]);
        *(bf16x8*)&ob[((size_t)(h+1)*WP_ + (w0+px+1))*64 + cs*8] = R.v;
    }
}

// ---------------------------------------------------------------------------
// Weight transpose+cast: w fp32 [O][64][9] -> wT bf16 [9][OPAD][64]
// ---------------------------------------------------------------------------
__global__ __launch_bounds__(256)
void cast_w_k(const float* __restrict__ w, __hip_bfloat16* __restrict__ wT,
              int O, int OPAD)
{
    const int idx = blockIdx.x*256 + threadIdx.x;
    if (idx >= 9*O*64) return;
    const int k = idx / (O*64);
    const int rem = idx - k*O*64;
    const int o = rem >> 6, c = rem & 63;
    wT[((size_t)k*OPAD + o)*64 + c] = __float2bfloat16(w[((size_t)o*64 + c)*9 + k]);
}

// ---------------------------------------------------------------------------
// Implicit-GEMM 3x3 conv via MFMA (R4-proven version: wA LDS tile, XOR
// swizzle, 2 barriers/tap). B = direct 16B NHWC loads at tap-shifted pos.
// ---------------------------------------------------------------------------
enum OutMode { OUT_NHWC_PAD_RELU, OUT_NCHW_F32, OUT_NCHW_BF16 };

template<int G, int CO_TOT, OutMode MODE>
__global__ __launch_bounds__(256)
void conv_mfma_k(const __hip_bfloat16* __restrict__ xT,
                 const __hip_bfloat16* __restrict__ wT, int o_total,
                 void* __restrict__ outp)
{
    __shared__ __hip_bfloat16 wA[64][64];
    const int tid = threadIdx.x, lane = tid & 63, wid = tid >> 6;
    const int l15 = lane & 15, khi = lane >> 4;
    const int ow0 = blockIdx.x*64, oh = blockIdx.y;
    const int b = blockIdx.z & 7, cob = blockIdx.z >> 3;
    const int px = wid*16 + l15;
    const __hip_bfloat16* xb = xT + (size_t)b*XPLANE_;

    f32x4 acc[G];
    const f32x4 vz = {0.f,0.f,0.f,0.f};
#pragma unroll
    for (int g=0; g<G; ++g) acc[g] = vz;

    for (int k=0; k<9; ++k){
        const int dy = k/3 - 1, dxk = k%3 - 1;
        __syncthreads();
        for (int i=tid; i<G*16*8; i+=256){
            const int o = i >> 3, cs = i & 7;
            *(bf16x8*)&wA[o][((cs ^ (o&7))*8)] =
                *(const bf16x8*)&wT[((size_t)k*o_total + cob*64 + o)*64 + cs*8];
        }
        __syncthreads();
        const int base = (((oh+1+dy)*WP_) + (ow0+px+1+dxk))*64;
#pragma unroll
        for (int s=0; s<2; ++s){
            const bf16x8 bfr = *(const bf16x8*)&xb[base + s*32 + khi*8];
            const int c8 = ((s*4 + khi) ^ (l15 & 7))*8;
#pragma unroll
            for (int g=0; g<G; ++g){
                const bf16x8 afr = *(const bf16x8*)&wA[g*16 + l15][c8];
                acc[g] = __builtin_amdgcn_mfma_f32_16x16x32_bf16(afr, bfr, acc[g], 0,0,0);
            }
        }
    }
    // ---- epilogue ----
    if (MODE == OUT_NHWC_PAD_RELU){
        __hip_bfloat16* ob = (__hip_bfloat16*)outp + (size_t)b*XPLANE_;
        const size_t orow = ((size_t)(oh+1)*WP_ + (ow0+px+1))*64;
#pragma unroll
        for (int g=0; g<G; ++g){
            union { short4 s4; __hip_bfloat16 h[4]; } o4;
#pragma unroll
            for (int r=0;r<4;r++) o4.h[r] = __float2bfloat16(fmaxf(acc[g][r], 0.f));
            *(short4*)&ob[orow + g*16 + khi*4] = o4.s4;
        }
    } else if (MODE == OUT_NCHW_F32){
        float* ob = (float*)outp;
#pragma unroll
        for (int g=0; g<G; ++g)
#pragma unroll
            for (int r=0;r<4;r++){
                const int co = cob*64 + g*16 + khi*4 + r;
                if (co < CO_TOT)
                    ob[(((size_t)b*CO_TOT + co)*H_ + oh)*W_ + ow0 + px] = acc[g][r];
            }
    } else {
        __hip_bfloat16* ob = (__hip_bfloat16*)outp;
#pragma unroll
        for (int g=0; g<G; ++g)
#pragma unroll
            for (int r=0;r<4;r++){
                const int co = cob*64 + g*16 + khi*4 + r;
                ob[(((size_t)b*CO_TOT + co)*H_ + oh)*W_ + ow0 + px] = __float2bfloat16(acc[g][r]);
            }
    }
}

// ---------------------------------------------------------------------------
// 4-corner bilinear blend of 8 consecutive channels (NHWC bf16) -> bf16x8.
// ---------------------------------------------------------------------------
__device__ __forceinline__ bf16x8 blend4(const __hip_bfloat16* __restrict__ xb,
                                         int a00, int dxo, int dro, float4 w)
{
    const u32x4 q00 = *(const u32x4*)(xb + a00);
    const u32x4 q01 = *(const u32x4*)(xb + a00 + dxo);
    const u32x4 q10 = *(const u32x4*)(xb + a00 + dro);
    const u32x4 q11 = *(const u32x4*)(xb + a00 + dro + dxo);
    union { bf16x8 v; __hip_bfloat16 h[8]; } R;
#pragma unroll
    for (int p=0;p<4;++p){
        const float l00 = __uint_as_float(q00[p]<<16), h00 = __uint_as_float(q00[p]&0xFFFF0000u);
        const float l01 = __uint_as_float(q01[p]<<16), h01 = __uint_as_float(q01[p]&0xFFFF0000u);
        const float l10 = __uint_as_float(q10[p]<<16), h10 = __uint_as_float(q10[p]&0xFFFF0000u);
        const float l11 = __uint_as_float(q11[p]<<16), h11 = __uint_as_float(q11[p]&0xFFFF0000u);
        R.h[2*p  ] = __float2bfloat16(w.x*l00 + w.y*l01 + w.z*l10 + w.w*l11);
        R.h[2*p+1] = __float2bfloat16(w.x*h00 + w.y*h01 + w.z*h10 + w.w*h11);
    }
    return R.v;
}

// ---------------------------------------------------------------------------
// Fused deformable conv (MFMA) + softmax attention, v3:
//  - per-thread inline meta (no meta LDS, no meta barriers)
//  - double-buffered wA tile, async-split staging (issue loads early,
//    ds_write late), ONE barrier per tap
//  - off-row values prefetched one tap ahead
// ---------------------------------------------------------------------------
__global__ __launch_bounds__(256)
void deform_att_k(const __hip_bfloat16* __restrict__ xT,
                  const float* __restrict__ off,
                  const __hip_bfloat16* __restrict__ att,
                  const __hip_bfloat16* __restrict__ wTd,   // [9][128][64]
                  float* __restrict__ out)
{
    __shared__ __hip_bfloat16 wA[2][64][64];
    const int tid = threadIdx.x, lane = tid & 63, wid = tid >> 6;
    const int l15 = lane & 15, khi = lane >> 4;
    const int ow0 = blockIdx.x*64, oh = blockIdx.y, b = blockIdx.z;
    const int px = wid*16 + l15;
    const __hip_bfloat16* xb = xT + (size_t)b*XPLANE_;
    const float* offb = off + (size_t)b*36*HW_ + (size_t)oh*W_ + ow0 + px;
    const int srow = tid >> 3, scs = tid & 7;     // staging: rows srow, srow+32
    const int swz = (scs ^ (srow & 7)) * 8;

    f32x4 acc[2][4];
    const f32x4 vz = {0.f,0.f,0.f,0.f};
#pragma unroll
    for (int d=0; d<2; ++d)
#pragma unroll
        for (int g=0; g<4; ++g) acc[d][g] = vz;

    // ---- prologue: stage tap (dk=0,k=0) weights; load its off rows ----
    {
        const bf16x8 p0 = *(const bf16x8*)&wTd[(size_t)srow*64 + scs*8];
        const bf16x8 p1 = *(const bf16x8*)&wTd[(size_t)(srow+32)*64 + scs*8];
        *(bf16x8*)&wA[0][srow   ][swz] = p0;
        *(bf16x8*)&wA[0][srow+32][swz] = p1;
    }
    float oyr = offb[0];
    float oxr = offb[HW_];
    __syncthreads();

#pragma unroll
    for (int dk=0; dk<2; ++dk){
        for (int k=0; k<9; ++k){
            const int t = dk*9 + k;
            // ---- issue next tap's global loads early (weights + off) ----
            bf16x8 nw0 = {}, nw1 = {};
            float noy = 0.f, nox = 0.f;
            const bool hn = (t < 17);
            const int ndk = (k==8) ? dk+1 : dk;
            const int nk  = (k==8) ? 0 : k+1;
            if (hn){
                const __hip_bfloat16* wsrc =
                    &wTd[((size_t)nk*128 + ndk*64 + srow)*64 + scs*8];
                nw0 = *(const bf16x8*)wsrc;
                nw1 = *(const bf16x8*)(wsrc + 32*64);
                noy = offb[(size_t)(ndk*18 + 2*nk    )*HW_];
                nox = offb[(size_t)(ndk*18 + 2*nk + 1)*HW_];
            }
            // ---- inline bilinear meta for this thread's px ----
            const int kr = k/3, kc = k - 3*kr;
            const float py  = (float)(oh  - 1 + kr) + oyr;
            const float pxx = (float)(ow0 + px - 1 + kc) + oxr;
            const float y0f = floorf(py), x0f = floorf(pxx);
            const float ay = py - y0f, ax = pxx - x0f;
            const int y0 = (int)y0f, x0 = (int)x0f;
            const int y1 = y0 + 1,   x1 = x0 + 1;
            const float my0 = (y0 >= 0 && y0 < H_) ? 1.f : 0.f;
            const float my1 = (y1 >= 0 && y1 < H_) ? 1.f : 0.f;
            const float mx0 = (x0 >= 0 && x0 < W_) ? 1.f : 0.f;
            const float mx1 = (x1 >= 0 && x1 < W_) ? 1.f : 0.f;
            const int y0c = min(max(y0,0),H_-1), y1c = min(max(y1,0),H_-1);
            const int x0c = min(max(x0,0),W_-1), x1c = min(max(x1,0),W_-1);
            const float wy0 = my0*(1.f-ay), wy1 = my1*ay;
            const float wx0 = mx0*(1.f-ax), wx1 = mx1*ax;
            const int   a00 = ((y0c+1)*WP_ + (x0c+1))*64;
            const int   dxo = (x1c-x0c)*64;
            const int   dro = (y1c-y0c)*WP_*64;
            const float4 w4 = make_float4(wy0*wx0, wy0*wx1, wy1*wx0, wy1*wx1);
            // ---- compute current tap from wA[t&1] ----
            const __hip_bfloat16 (*wr)[64] =
                (const __hip_bfloat16 (*)[64])wA[t & 1];
#pragma unroll
            for (int s=0; s<2; ++s){
                const bf16x8 bfr = blend4(xb, a00 + s*32 + khi*8, dxo, dro, w4);
                const int c8 = ((s*4 + khi) ^ (l15 & 7))*8;
#pragma unroll
                for (int g=0; g<4; ++g){
                    const bf16x8 afr = *(const bf16x8*)&wr[g*16 + l15][c8];
                    acc[dk][g] = __builtin_amdgcn_mfma_f32_16x16x32_bf16(afr, bfr, acc[dk][g], 0,0,0);
                }
            }
            // ---- late ds_write of the prefetched tap; rotate off regs ----
            if (hn){
                *(bf16x8*)&wA[(t+1) & 1][srow   ][swz] = nw0;
                *(bf16x8*)&wA[(t+1) & 1][srow+32][swz] = nw1;
                oyr = noy; oxr = nox;
            }
            __syncthreads();
        }
    }
    // ---- epilogue: softmax over the 2 dynamic branches + write ----
#pragma unroll
    for (int g=0; g<4; ++g)
#pragma unroll
        for (int r=0; r<4; ++r){
            const int co = g*16 + khi*4 + r;
            const float a0 = __bfloat162float(att[(((size_t)b*128      + co)*H_ + oh)*W_ + ow0 + px]);
            const float a1 = __bfloat162float(att[(((size_t)b*128 + 64 + co)*H_ + oh)*W_ + ow0 + px]);
            const float f0 = 1.f / (1.f + __expf(a1 - a0));
            out[(((size_t)b*64 + co)*H_ + oh)*W_ + ow0 + px] =
                acc[0][g][r]*f0 + acc[1][g][r]*(1.f - f0);
        }
}

// ---------------------------------------------------------------------------
extern "C" void kernel_launch(void* const* d_in, const int* in_sizes, int n_in,
                              void* d_out, int out_size, void* d_ws, size_t ws_size,
                              hipStream_t stream)
{
    const float* x  = (const float*)d_in[0];
    const float* w1 = (const float*)d_in[1];
    const float* w2 = (const float*)d_in[2];
    const float* w3 = (const float*)d_in[3];
    const float* wa = (const float*)d_in[4];
    const float* wd = (const float*)d_in[5];
    float* out = (float*)d_out;

    // ---- workspace layout (halfword units for bf16 regions) ----
    __hip_bfloat16* xTp  = (__hip_bfloat16*)d_ws;       // 8,652,800
    __hip_bfloat16* m1Tp = xTp  + (size_t)8652800;      // 8,652,800
    __hip_bfloat16* m2Tp = m1Tp + (size_t)8652800;      // 8,652,800
    __hip_bfloat16* wT1  = m2Tp + (size_t)8652800;      // 9*64*64   = 36864
    __hip_bfloat16* wT2  = wT1  + 36864;                // 36864
    __hip_bfloat16* wT3  = wT2  + 36864;                // 9*48*64   = 27648
    __hip_bfloat16* wTa  = wT3  + 27648;                // 9*128*64  = 73728
    __hip_bfloat16* wTd  = wTa  + 73728;                // 73728
    float*          offs = (float*)(wTd + 73728);       // 8*36*128*128 fp32
    __hip_bfloat16* att16 = m1Tp;   // aliases m1Tp+m2Tp (both dead by then)

    const dim3 blk(256);
    // zero padded NHWC buffers (halos) + wT3 pad rows
    zero_k<<<dim3(2048), blk, 0, stream>>>((unsigned int*)xTp, 12979200);
    zero_k<<<dim3(54),   blk, 0, stream>>>((unsigned int*)wT3, 13824);
    // layout transforms
    xpose_x_k<<<dim3(2,128,8), blk, 0, stream>>>(x, xTp);
    cast_w_k<<<dim3(144), blk, 0, stream>>>(w1, wT1,  64,  64);
    cast_w_k<<<dim3(144), blk, 0, stream>>>(w2, wT2,  64,  64);
    cast_w_k<<<dim3(81),  blk, 0, stream>>>(w3, wT3,  36,  48);
    cast_w_k<<<dim3(288), blk, 0, stream>>>(wa, wTa, 128, 128);
    cast_w_k<<<dim3(288), blk, 0, stream>>>(wd, wTd, 128, 128);
    // conv chain (implicit-GEMM MFMA, R4 structure)
    conv_mfma_k<4,  64, OUT_NHWC_PAD_RELU><<<dim3(2,128,8),  blk, 0, stream>>>(xTp,  wT1,  64, m1Tp);
    conv_mfma_k<4,  64, OUT_NHWC_PAD_RELU><<<dim3(2,128,8),  blk, 0, stream>>>(m1Tp, wT2,  64, m2Tp);
    conv_mfma_k<3,  36, OUT_NCHW_F32     ><<<dim3(2,128,8),  blk, 0, stream>>>(m2Tp, wT3,  48, offs);
    conv_mfma_k<4, 128, OUT_NCHW_BF16    ><<<dim3(2,128,16), blk, 0, stream>>>(xTp,  wTa, 128, att16);
    // fused deformable conv + attention (v3)
    deform_att_k<<<dim3(2,128,8), blk, 0, stream>>>(xTp, offs, att16, wTd, out);
}

// Round 7
// 289.278 us; speedup vs baseline: 2.4458x; 1.0600x over previous
//
#include <hip/hip_runtime.h>
#include <hip/hip_bf16.h>
#include <math.h>

#define B_ 8
#define C_ 64
#define H_ 128
#define W_ 128
#define HW_ (H_*W_)
#define HP_ 130
#define WP_ 130
#define XPLANE_ (HP_*WP_*64)     // padded NHWC plane per batch (halfwords)

typedef __attribute__((ext_vector_type(8))) short bf16x8;
typedef __attribute__((ext_vector_type(4))) float f32x4;
typedef __attribute__((ext_vector_type(4))) unsigned int u32x4;

// ---------------------------------------------------------------------------
// Zero only the 1-px halo ring of the 3 padded NHWC planes (blocks 0..23)
// and the wT3 pad region (block 24). ~2 MB instead of 52 MB.
// ---------------------------------------------------------------------------
__global__ __launch_bounds__(256)
void zero_halo_k(unsigned int* __restrict__ planes, unsigned int* __restrict__ wT3u)
{
    const int blk = blockIdx.x;
    if (blk < 24){
        const int plane = blk >> 3, batch = blk & 7;
        unsigned int* base = planes + (size_t)plane*4326400 + (size_t)batch*(XPLANE_/2);
        for (int i = threadIdx.x; i < 516*32; i += 256){
            const int u = i & 31, p = i >> 5;
            int h, w;
            if (p < 130)      { h = 0;        w = p;       }
            else if (p < 260) { h = 129;      w = p - 130; }
            else if (p < 388) { h = p - 259;  w = 0;       }
            else              { h = p - 387;  w = 129;     }
            base[(size_t)(h*130 + w)*32 + u] = 0u;
        }
    } else {
        for (int i = threadIdx.x; i < 13824; i += 256) wT3u[i] = 0u;
    }
}

// ---------------------------------------------------------------------------
// x NCHW fp32 -> xTp padded NHWC bf16 (interior only; halo pre-zeroed).
// ---------------------------------------------------------------------------
__global__ __launch_bounds__(256)
void xpose_x_k(const float* __restrict__ x, __hip_bfloat16* __restrict__ xTp)
{
    __shared__ float tile[64][65];
    const int tid = threadIdx.x;
    const int w0 = blockIdx.x*64, h = blockIdx.y, b = blockIdx.z;
    const float* xb = x + (size_t)b*64*HW_;
    for (int i = tid; i < 4096; i += 256){
        const int c = i >> 6, px = i & 63;
        tile[c][px] = xb[(size_t)c*HW_ + h*W_ + w0 + px];
    }
    __syncthreads();
    __hip_bfloat16* ob = xTp + (size_t)b*XPLANE_;
    for (int i = tid; i < 512; i += 256){
        const int px = i >> 3, cs = i & 7;
        union { bf16x8 v; __hip_bfloat16 h8[8]; } R;
#pragma unroll
        for (int j=0;j<8;j++) R.h8[j] = __float2bfloat16(tile[cs*8+j][px]);
        *(bf16x8*)&ob[((size_t)(h+1)*WP_ + (w0+px+1))*64 + cs*8] = R.v;
    }
}

// ---------------------------------------------------------------------------
// All weight transposes+casts in one launch: w fp32 [O][64][9] -> bf16 [9][OPAD][64]
// ---------------------------------------------------------------------------
__device__ __forceinline__ void cast_one(const float* __restrict__ w,
                                         __hip_bfloat16* __restrict__ wT,
                                         int O, int OPAD, int idx)
{
    if (idx >= 9*O*64) return;
    const int k = idx / (O*64);
    const int rem = idx - k*O*64;
    const int o = rem >> 6, c = rem & 63;
    wT[((size_t)k*OPAD + o)*64 + c] = __float2bfloat16(w[((size_t)o*64 + c)*9 + k]);
}

__global__ __launch_bounds__(256)
void cast_all_k(const float* __restrict__ w1, const float* __restrict__ w2,
                const float* __restrict__ w3, const float* __restrict__ wa,
                const float* __restrict__ wd,
                __hip_bfloat16* __restrict__ wT1, __hip_bfloat16* __restrict__ wT2,
                __hip_bfloat16* __restrict__ wT3, __hip_bfloat16* __restrict__ wTa,
                __hip_bfloat16* __restrict__ wTd)
{
    const int bx = blockIdx.x, tid = threadIdx.x;
    if      (bx < 144) cast_one(w1, wT1,  64,  64, bx*256 + tid);
    else if (bx < 288) cast_one(w2, wT2,  64,  64, (bx-144)*256 + tid);
    else if (bx < 369) cast_one(w3, wT3,  36,  48, (bx-288)*256 + tid);
    else if (bx < 657) cast_one(wa, wTa, 128, 128, (bx-369)*256 + tid);
    else               cast_one(wd, wTd, 128, 128, (bx-657)*256 + tid);
}

// ---------------------------------------------------------------------------
// Implicit-GEMM 3x3 conv via MFMA (R4-proven version: wA LDS tile, XOR
// swizzle, 2 barriers/tap). B = direct 16B NHWC loads at tap-shifted pos.
// ---------------------------------------------------------------------------
enum OutMode { OUT_NHWC_PAD_RELU, OUT_NCHW_F32, OUT_NCHW_BF16 };

template<int G, int CO_TOT, OutMode MODE>
__global__ __launch_bounds__(256)
void conv_mfma_k(const __hip_bfloat16* __restrict__ xT,
                 const __hip_bfloat16* __restrict__ wT, int o_total,
                 void* __restrict__ outp)
{
    __shared__ __hip_bfloat16 wA[64][64];
    const int tid = threadIdx.x, lane = tid & 63, wid = tid >> 6;
    const int l15 = lane & 15, khi = lane >> 4;
    const int ow0 = blockIdx.x*64, oh = blockIdx.y;
    const int b = blockIdx.z & 7, cob = blockIdx.z >> 3;
    const int px = wid*16 + l15;
    const __hip_bfloat16* xb = xT + (size_t)b*XPLANE_;

    f32x4 acc[G];
    const f32x4 vz = {0.f,0.f,0.f,0.f};
#pragma unroll
    for (int g=0; g<G; ++g) acc[g] = vz;

    for (int k=0; k<9; ++k){
        const int dy = k/3 - 1, dxk = k%3 - 1;
        __syncthreads();
        for (int i=tid; i<G*16*8; i+=256){
            const int o = i >> 3, cs = i & 7;
            *(bf16x8*)&wA[o][((cs ^ (o&7))*8)] =
                *(const bf16x8*)&wT[((size_t)k*o_total + cob*64 + o)*64 + cs*8];
        }
        __syncthreads();
        const int base = (((oh+1+dy)*WP_) + (ow0+px+1+dxk))*64;
#pragma unroll
        for (int s=0; s<2; ++s){
            const bf16x8 bfr = *(const bf16x8*)&xb[base + s*32 + khi*8];
            const int c8 = ((s*4 + khi) ^ (l15 & 7))*8;
#pragma unroll
            for (int g=0; g<G; ++g){
                const bf16x8 afr = *(const bf16x8*)&wA[g*16 + l15][c8];
                acc[g] = __builtin_amdgcn_mfma_f32_16x16x32_bf16(afr, bfr, acc[g], 0,0,0);
            }
        }
    }
    // ---- epilogue ----
    if (MODE == OUT_NHWC_PAD_RELU){
        __hip_bfloat16* ob = (__hip_bfloat16*)outp + (size_t)b*XPLANE_;
        const size_t orow = ((size_t)(oh+1)*WP_ + (ow0+px+1))*64;
#pragma unroll
        for (int g=0; g<G; ++g){
            union { short4 s4; __hip_bfloat16 h[4]; } o4;
#pragma unroll
            for (int r=0;r<4;r++) o4.h[r] = __float2bfloat16(fmaxf(acc[g][r], 0.f));
            *(short4*)&ob[orow + g*16 + khi*4] = o4.s4;
        }
    } else if (MODE == OUT_NCHW_F32){
        float* ob = (float*)outp;
#pragma unroll
        for (int g=0; g<G; ++g)
#pragma unroll
            for (int r=0;r<4;r++){
                const int co = cob*64 + g*16 + khi*4 + r;
                if (co < CO_TOT)
                    ob[(((size_t)b*CO_TOT + co)*H_ + oh)*W_ + ow0 + px] = acc[g][r];
            }
    } else {
        __hip_bfloat16* ob = (__hip_bfloat16*)outp;
#pragma unroll
        for (int g=0; g<G; ++g)
#pragma unroll
            for (int r=0;r<4;r++){
                const int co = cob*64 + g*16 + khi*4 + r;
                ob[(((size_t)b*CO_TOT + co)*H_ + oh)*W_ + ow0 + px] = __float2bfloat16(acc[g][r]);
            }
    }
}

// ---------------------------------------------------------------------------
// 4-corner bilinear blend of 8 consecutive channels (NHWC bf16) -> bf16x8.
// ---------------------------------------------------------------------------
__device__ __forceinline__ bf16x8 blend4(const __hip_bfloat16* __restrict__ xb,
                                         int a00, int dxo, int dro, float4 w)
{
    const u32x4 q00 = *(const u32x4*)(xb + a00);
    const u32x4 q01 = *(const u32x4*)(xb + a00 + dxo);
    const u32x4 q10 = *(const u32x4*)(xb + a00 + dro);
    const u32x4 q11 = *(const u32x4*)(xb + a00 + dro + dxo);
    union { bf16x8 v; __hip_bfloat16 h[8]; } R;
#pragma unroll
    for (int p=0;p<4;++p){
        const float l00 = __uint_as_float(q00[p]<<16), h00 = __uint_as_float(q00[p]&0xFFFF0000u);
        const float l01 = __uint_as_float(q01[p]<<16), h01 = __uint_as_float(q01[p]&0xFFFF0000u);
        const float l10 = __uint_as_float(q10[p]<<16), h10 = __uint_as_float(q10[p]&0xFFFF0000u);
        const float l11 = __uint_as_float(q11[p]<<16), h11 = __uint_as_float(q11[p]&0xFFFF0000u);
        R.h[2*p  ] = __float2bfloat16(w.x*l00 + w.y*l01 + w.z*l10 + w.w*l11);
        R.h[2*p+1] = __float2bfloat16(w.x*h00 + w.y*h01 + w.z*h10 + w.w*h11);
    }
    return R.v;
}

// ---------------------------------------------------------------------------
struct Meta { int a00, dxo, dro; float4 w4; };

__device__ __forceinline__ Meta mkmeta(int oh, int ow0, int px, int k,
                                       float oy, float ox)
{
    const int kr = k/3, kc = k - 3*kr;
    const float py  = (float)(oh  - 1 + kr) + oy;
    const float pxx = (float)(ow0 + px - 1 + kc) + ox;
    const float y0f = floorf(py), x0f = floorf(pxx);
    const float ay = py - y0f, ax = pxx - x0f;
    const int y0 = (int)y0f, x0 = (int)x0f;
    const int y1 = y0 + 1,   x1 = x0 + 1;
    const float my0 = (y0 >= 0 && y0 < H_) ? 1.f : 0.f;
    const float my1 = (y1 >= 0 && y1 < H_) ? 1.f : 0.f;
    const float mx0 = (x0 >= 0 && x0 < W_) ? 1.f : 0.f;
    const float mx1 = (x1 >= 0 && x1 < W_) ? 1.f : 0.f;
    const int y0c = min(max(y0,0),H_-1), y1c = min(max(y1,0),H_-1);
    const int x0c = min(max(x0,0),W_-1), x1c = min(max(x1,0),W_-1);
    const float wy0 = my0*(1.f-ay), wy1 = my1*ay;
    const float wx0 = mx0*(1.f-ax), wx1 = mx1*ax;
    Meta m;
    m.a00 = ((y0c+1)*WP_ + (x0c+1))*64;
    m.dxo = (x1c-x0c)*64;
    m.dro = (y1c-y0c)*WP_*64;
    m.w4  = make_float4(wy0*wx0, wy0*wx1, wy1*wx0, wy1*wx1);
    return m;
}

// ---------------------------------------------------------------------------
// Fused deformable conv (MFMA) + softmax attention, v4:
//  - tap-outer / dk-inner: per tap, BOTH dk's weight tiles staged (16KB),
//    both dk's meta+blend+MFMA inside ONE barrier interval -> 9 barriers,
//    16 gathers in flight per interval.
//  - double-buffered wA, async-split staging (loads early, ds_write late).
// ---------------------------------------------------------------------------
__global__ __launch_bounds__(256)
void deform_att_k(const __hip_bfloat16* __restrict__ xT,
                  const float* __restrict__ off,
                  const __hip_bfloat16* __restrict__ att,
                  const __hip_bfloat16* __restrict__ wTd,   // [9][128][64]
                  float* __restrict__ out)
{
    __shared__ __hip_bfloat16 wA[2][2][64][64];   // [buf][dk][co][c]
    const int tid = threadIdx.x, lane = tid & 63, wid = tid >> 6;
    const int l15 = lane & 15, khi = lane >> 4;
    const int ow0 = blockIdx.x*64, oh = blockIdx.y, b = blockIdx.z;
    const int px = wid*16 + l15;
    const __hip_bfloat16* xb = xT + (size_t)b*XPLANE_;
    const float* offb = off + (size_t)b*36*HW_ + (size_t)oh*W_ + ow0 + px;
    const int srow = tid >> 3, scs = tid & 7;
    const int swz = (scs ^ (srow & 7)) * 8;

    f32x4 acc[2][4];
    const f32x4 vz = {0.f,0.f,0.f,0.f};
#pragma unroll
    for (int d=0; d<2; ++d)
#pragma unroll
        for (int g=0; g<4; ++g) acc[d][g] = vz;

    // ---- prologue: stage tap k=0, both dk; load k=0 off rows ----
    {
        const __hip_bfloat16* ws0 = &wTd[(size_t)srow*64 + scs*8];
        *(bf16x8*)&wA[0][0][srow   ][swz] = *(const bf16x8*)ws0;
        *(bf16x8*)&wA[0][0][srow+32][swz] = *(const bf16x8*)(ws0 + 32*64);
        *(bf16x8*)&wA[0][1][srow   ][swz] = *(const bf16x8*)(ws0 + 64*64);
        *(bf16x8*)&wA[0][1][srow+32][swz] = *(const bf16x8*)(ws0 + 96*64);
    }
    float oyr0 = offb[0],                 oxr0 = offb[HW_];
    float oyr1 = offb[(size_t)18*HW_],    oxr1 = offb[(size_t)19*HW_];
    __syncthreads();

    for (int k=0; k<9; ++k){
        // ---- issue next tap's global loads early ----
        bf16x8 nw00 = {}, nw01 = {}, nw10 = {}, nw11 = {};
        float noy0=0.f, nox0=0.f, noy1=0.f, nox1=0.f;
        const bool hn = (k < 8);
        if (hn){
            const __hip_bfloat16* ws0 = &wTd[((size_t)(k+1)*128 + srow)*64 + scs*8];
            nw00 = *(const bf16x8*)ws0;
            nw01 = *(const bf16x8*)(ws0 + 32*64);
            nw10 = *(const bf16x8*)(ws0 + 64*64);
            nw11 = *(const bf16x8*)(ws0 + 96*64);
            noy0 = offb[(size_t)(2*k+2)*HW_];
            nox0 = offb[(size_t)(2*k+3)*HW_];
            noy1 = offb[(size_t)(2*k+20)*HW_];
            nox1 = offb[(size_t)(2*k+21)*HW_];
        }
        // ---- meta for both dk ----
        const Meta m0 = mkmeta(oh, ow0, px, k, oyr0, oxr0);
        const Meta m1 = mkmeta(oh, ow0, px, k, oyr1, oxr1);
        const __hip_bfloat16 (*wr0)[64] = (const __hip_bfloat16 (*)[64])wA[k & 1][0];
        const __hip_bfloat16 (*wr1)[64] = (const __hip_bfloat16 (*)[64])wA[k & 1][1];
        // ---- both dk's blend + MFMA per s ----
#pragma unroll
        for (int s=0; s<2; ++s){
            const bf16x8 b0 = blend4(xb, m0.a00 + s*32 + khi*8, m0.dxo, m0.dro, m0.w4);
            const bf16x8 b1 = blend4(xb, m1.a00 + s*32 + khi*8, m1.dxo, m1.dro, m1.w4);
            const int c8 = ((s*4 + khi) ^ (l15 & 7))*8;
#pragma unroll
            for (int g=0; g<4; ++g){
                const bf16x8 a0 = *(const bf16x8*)&wr0[g*16 + l15][c8];
                acc[0][g] = __builtin_amdgcn_mfma_f32_16x16x32_bf16(a0, b0, acc[0][g], 0,0,0);
            }
#pragma unroll
            for (int g=0; g<4; ++g){
                const bf16x8 a1 = *(const bf16x8*)&wr1[g*16 + l15][c8];
                acc[1][g] = __builtin_amdgcn_mfma_f32_16x16x32_bf16(a1, b1, acc[1][g], 0,0,0);
            }
        }
        // ---- late ds_write of prefetched tap; rotate off regs ----
        if (hn){
            *(bf16x8*)&wA[(k+1)&1][0][srow   ][swz] = nw00;
            *(bf16x8*)&wA[(k+1)&1][0][srow+32][swz] = nw01;
            *(bf16x8*)&wA[(k+1)&1][1][srow   ][swz] = nw10;
            *(bf16x8*)&wA[(k+1)&1][1][srow+32][swz] = nw11;
            oyr0 = noy0; oxr0 = nox0; oyr1 = noy1; oxr1 = nox1;
        }
        __syncthreads();
    }
    // ---- epilogue: softmax over the 2 dynamic branches + write ----
#pragma unroll
    for (int g=0; g<4; ++g)
#pragma unroll
        for (int r=0; r<4; ++r){
            const int co = g*16 + khi*4 + r;
            const float a0 = __bfloat162float(att[(((size_t)b*128      + co)*H_ + oh)*W_ + ow0 + px]);
            const float a1 = __bfloat162float(att[(((size_t)b*128 + 64 + co)*H_ + oh)*W_ + ow0 + px]);
            const float f0 = 1.f / (1.f + __expf(a1 - a0));
            out[(((size_t)b*64 + co)*H_ + oh)*W_ + ow0 + px] =
                acc[0][g][r]*f0 + acc[1][g][r]*(1.f - f0);
        }
}

// ---------------------------------------------------------------------------
extern "C" void kernel_launch(void* const* d_in, const int* in_sizes, int n_in,
                              void* d_out, int out_size, void* d_ws, size_t ws_size,
                              hipStream_t stream)
{
    const float* x  = (const float*)d_in[0];
    const float* w1 = (const float*)d_in[1];
    const float* w2 = (const float*)d_in[2];
    const float* w3 = (const float*)d_in[3];
    const float* wa = (const float*)d_in[4];
    const float* wd = (const float*)d_in[5];
    float* out = (float*)d_out;

    // ---- workspace layout (halfword units for bf16 regions) ----
    __hip_bfloat16* xTp  = (__hip_bfloat16*)d_ws;       // 8,652,800
    __hip_bfloat16* m1Tp = xTp  + (size_t)8652800;      // 8,652,800
    __hip_bfloat16* m2Tp = m1Tp + (size_t)8652800;      // 8,652,800
    __hip_bfloat16* wT1  = m2Tp + (size_t)8652800;      // 9*64*64   = 36864
    __hip_bfloat16* wT2  = wT1  + 36864;                // 36864
    __hip_bfloat16* wT3  = wT2  + 36864;                // 9*48*64   = 27648
    __hip_bfloat16* wTa  = wT3  + 27648;                // 9*128*64  = 73728
    __hip_bfloat16* wTd  = wTa  + 73728;                // 73728
    float*          offs = (float*)(wTd + 73728);       // 8*36*128*128 fp32
    __hip_bfloat16* att16 = m1Tp;   // aliases m1Tp+m2Tp (both dead by then)

    const dim3 blk(256);
    // halo-only zeroing of the 3 padded planes + wT3 pad
    zero_halo_k<<<dim3(25), blk, 0, stream>>>((unsigned int*)xTp, (unsigned int*)wT3);
    // layout transforms
    xpose_x_k<<<dim3(2,128,8), blk, 0, stream>>>(x, xTp);
    cast_all_k<<<dim3(945), blk, 0, stream>>>(w1,w2,w3,wa,wd, wT1,wT2,wT3,wTa,wTd);
    // conv chain (implicit-GEMM MFMA, R4 structure)
    conv_mfma_k<4,  64, OUT_NHWC_PAD_RELU><<<dim3(2,128,8),  blk, 0, stream>>>(xTp,  wT1,  64, m1Tp);
    conv_mfma_k<4,  64, OUT_NHWC_PAD_RELU><<<dim3(2,128,8),  blk, 0, stream>>>(m1Tp, wT2,  64, m2Tp);
    conv_mfma_k<3,  36, OUT_NCHW_F32     ><<<dim3(2,128,8),  blk, 0, stream>>>(m2Tp, wT3,  48, offs);
    conv_mfma_k<4, 128, OUT_NCHW_BF16    ><<<dim3(2,128,16), blk, 0, stream>>>(xTp,  wTa, 128, att16);
    // fused deformable conv + attention (v4: tap-outer, dk-inner)
    deform_att_k<<<dim3(2,128,8), blk, 0, stream>>>(xTp, offs, att16, wTd, out);
}